// Round 3
// baseline (233.853 us; speedup 1.0000x reference)
//
#include <hip/hip_runtime.h>
#include <hip/hip_bf16.h>
#include <cmath>

// ---------- problem constants ----------
constexpr int CB = 8, CS = 2048, CDV = 768, CDA = 512, CK = 512;
constexpr int CM = CB * CS;             // 16384 rows (b,s)

// ---------- types ----------
typedef __attribute__((ext_vector_type(8))) short  s8v;   // 8 bf16 (4 VGPRs)
typedef __attribute__((ext_vector_type(4))) short  s4v;   // 4 bf16
typedef __attribute__((ext_vector_type(4))) float  f4v;   // MFMA acc

__device__ __forceinline__ unsigned short f2bf(float x) {
    union { float f; unsigned int u; } c; c.f = x;
    unsigned int u = c.u;
    u += 0x7fffu + ((u >> 16) & 1u);    // RNE (inputs finite)
    return (unsigned short)(u >> 16);
}

// ---------- prep: bf16 convert + window-3 temporal smooth (both modalities) ----------
template<int D>
__device__ __forceinline__ void smooth_one(const float* __restrict__ f,
                                           unsigned short* __restrict__ g,
                                           unsigned short* __restrict__ sm,
                                           int idx)
{
    int dchunk = idx % (D / 4);
    int bs     = idx / (D / 4);
    int s      = bs % CS;
    const f4v* fp = (const f4v*)f;
    int base = bs * (D / 4) + dchunk;
    f4v cur = fp[base];
    f4v acc = cur;
    float cnt = 1.f;
    if (s > 0)      { acc += fp[base - D / 4]; cnt += 1.f; }
    if (s < CS - 1) { acc += fp[base + D / 4]; cnt += 1.f; }
    float inv = 1.f / cnt;
    s4v gp, sp;
#pragma unroll
    for (int j = 0; j < 4; ++j) {
        gp[j] = (short)f2bf(cur[j]);
        sp[j] = (short)f2bf(acc[j] * inv);
    }
    ((s4v*)g)[base]  = gp;
    ((s4v*)sm)[base] = sp;
}

__global__ void prep_smooth_all(const float* __restrict__ fv, const float* __restrict__ fa,
                                unsigned short* __restrict__ Gv, unsigned short* __restrict__ Sv,
                                unsigned short* __restrict__ Ga, unsigned short* __restrict__ Sa)
{
    int idx = blockIdx.x * 256 + threadIdx.x;
    constexpr int NV = CM * (CDV / 4);
    constexpr int NA = CM * (CDA / 4);
    if (idx < NV)            smooth_one<CDV>(fv, Gv, Sv, idx);
    else if (idx < NV + NA)  smooth_one<CDA>(fa, Ga, Sa, idx - NV);
}

// ---------- small prep: proto convert + proj transpose (one launch) ----------
__device__ __forceinline__ void conv4(const float* __restrict__ in,
                                      unsigned short* __restrict__ out, int i)
{
    f4v v = ((const f4v*)in)[i];
    s4v o;
#pragma unroll
    for (int j = 0; j < 4; ++j) o[j] = (short)f2bf(v[j]);
    ((s4v*)out)[i] = o;
}

__global__ void prep_small(const float* __restrict__ pv, const float* __restrict__ pa,
                           const float* __restrict__ wv, const float* __restrict__ wa,
                           unsigned short* __restrict__ Pv, unsigned short* __restrict__ Pa,
                           unsigned short* __restrict__ WvT, unsigned short* __restrict__ WaT)
{
    int idx = blockIdx.x * 256 + threadIdx.x;
    constexpr int N1 = CK * CDV / 4;
    constexpr int N2 = CK * CDA / 4;
    constexpr int N3 = CDV * CDA;
    constexpr int N4 = CDV * CDA;
    if (idx < N1) { conv4(pv, Pv, idx); return; }
    idx -= N1;
    if (idx < N2) { conv4(pa, Pa, idx); return; }
    idx -= N2;
    if (idx < N3) {   // wv (768x512) -> WvT (512x768)
        int r = idx % CDV, c = idx / CDV;
        WvT[(size_t)c * CDV + r] = f2bf(wv[(size_t)r * CDA + c]);
        return;
    }
    idx -= N3;
    if (idx < N4) {   // wa (512x768) -> WaT (768x512)
        int r = idx % CDA, c = idx / CDA;
        WaT[(size_t)c * CDA + r] = f2bf(wa[(size_t)r * CDV + c]);
    }
}

// ---------- GEMM tile engine: acc += A(M,D) @ BT(N,D)^T on a 128x128 tile ----------
// 256 threads = 4 waves; 128x128 tile; wave owns 64x64 (4x4 frags of 16x16x32).
// 2-PHASE double-buffered pipeline (minimum 2-phase recipe):
//   prologue: STAGE(buf0); vmcnt(0); barrier
//   loop:     STAGE(buf^1, t+1)  ||  ds_read(buf) + MFMA;  vmcnt(0); barrier; swap
// LDS linear per buffer [128][64] shorts; both-sides XOR chunk swizzle
// (source chunk ^= row&7, same XOR on fragment reads) -> conflict-free (verified R2).
__device__ __forceinline__ void gemm_phase(
    const unsigned short* __restrict__ A,
    const unsigned short* __restrict__ BT,
    int D, int bm, int bn, int tid,
    unsigned short* As, unsigned short* Bs,   // each 2 * 128*64 shorts (32 KB)
    f4v (&acc)[4][4])
{
    const int lane = tid & 63;
    const int w    = tid >> 6;
    const int wr   = (w >> 1) * 64;
    const int wc   = (w & 1) * 64;
    const int lr   = lane & 15;
    const int hi   = lane >> 4;

    // hoisted per-thread staging bases (K-loop only adds d0)
    const unsigned short* gA[4];
    const unsigned short* gB[4];
    int wb[4];
#pragma unroll
    for (int it = 0; it < 4; ++it) {
        int idx = it * 256 + tid;
        int row = idx >> 3;
        int sch = (idx & 7) ^ (row & 7);            // pre-swizzled source chunk
        wb[it]  = (idx & ~63) * 8;                  // wave-uniform LDS base (shorts)
        gA[it]  = A  + (size_t)(bm + row) * D + sch * 8;
        gB[it]  = BT + (size_t)(bn + row) * D + sch * 8;
    }

    auto stage = [&](int buf, int d0) {
#pragma unroll
        for (int it = 0; it < 4; ++it) {
            __builtin_amdgcn_global_load_lds(
                (const __attribute__((address_space(1))) unsigned int*)(gA[it] + d0),
                (__attribute__((address_space(3))) unsigned int*)(As + buf * 8192 + wb[it]),
                16, 0, 0);
            __builtin_amdgcn_global_load_lds(
                (const __attribute__((address_space(1))) unsigned int*)(gB[it] + d0),
                (__attribute__((address_space(3))) unsigned int*)(Bs + buf * 8192 + wb[it]),
                16, 0, 0);
        }
    };

    __syncthreads();                   // all waves done reading LDS (previous phase)
    stage(0, 0);
    asm volatile("s_waitcnt vmcnt(0)" ::: "memory");
    __syncthreads();

    const int nt = D >> 6;
    int cur = 0;
    for (int t = 0; t < nt; ++t) {
        if (t + 1 < nt) stage(cur ^ 1, (t + 1) << 6);   // prefetch overlaps compute
        const unsigned short* Ab = As + cur * 8192;
        const unsigned short* Bb = Bs + cur * 8192;
#pragma unroll
        for (int kk = 0; kk < 2; ++kk) {
            s8v af[4], bfr[4];
#pragma unroll
            for (int f = 0; f < 4; ++f) {
                int ar = wr + f * 16 + lr;
                int ac = ((kk * 4 + hi) ^ (ar & 7)) * 8;   // swizzled read
                af[f]  = *(const s8v*)(Ab + ar * 64 + ac);
                int br = wc + f * 16 + lr;
                int bc = ((kk * 4 + hi) ^ (br & 7)) * 8;
                bfr[f] = *(const s8v*)(Bb + br * 64 + bc);
            }
#pragma unroll
            for (int i = 0; i < 4; ++i)
#pragma unroll
                for (int j = 0; j < 4; ++j)
                    acc[i][j] = __builtin_amdgcn_mfma_f32_16x16x32_bf16(
                        af[i], bfr[j], acc[i][j], 0, 0, 0);
        }
        if (t + 1 < nt) {
            asm volatile("s_waitcnt vmcnt(0)" ::: "memory");  // prefetch landed
            __syncthreads();                                   // safe to reuse buffers
            cur ^= 1;
        }
    }
}

// ---------- combine GEMMs (both modalities, one launch), bf16 out ----------
__global__ void __launch_bounds__(256)
gemm_combine2(const unsigned short* __restrict__ Pv, const unsigned short* __restrict__ WvT,
              unsigned short* __restrict__ Cv,
              const unsigned short* __restrict__ Pa, const unsigned short* __restrict__ WaT,
              unsigned short* __restrict__ Ca)
{
    __shared__ __align__(16) unsigned short As[2 * 128 * 64];
    __shared__ __align__(16) unsigned short Bs[2 * 128 * 64];
    int id = blockIdx.x;
    const unsigned short *A, *BT; unsigned short* C; int D, N, bm, bn;
    if (id < 16) { A = Pv; BT = WvT; C = Cv; D = CDV; N = CDA; bm = (id & 3) * 128; bn = (id >> 2) * 128; }
    else { id -= 16; A = Pa; BT = WaT; C = Ca; D = CDA; N = CDV; bm = (id & 3) * 128; bn = (id >> 2) * 128; }

    f4v acc[4][4] = {};
    int tid = threadIdx.x;
    gemm_phase(A, BT, D, bm, bn, tid, As, Bs, acc);

    const int lane = tid & 63;
    const int w    = tid >> 6;
    const int wr   = (w >> 1) * 64, wc = (w & 1) * 64;
    const int row0 = (lane >> 4) * 4, col = lane & 15;   // C/D map: col=lane&15, row=(lane>>4)*4+e
#pragma unroll
    for (int i = 0; i < 4; ++i)
#pragma unroll
        for (int j = 0; j < 4; ++j)
#pragma unroll
            for (int e = 0; e < 4; ++e) {
                int m = bm + wr + i * 16 + row0 + e;
                int n = bn + wc + j * 16 + col;
                C[(size_t)m * N + n] = f2bf(acc[i][j][e]);
            }
}

// ---------- fused dual-GEMM + softplus-energy reduce (both modalities via z) ----------
__global__ void __launch_bounds__(256)
fused_energy(const unsigned short* __restrict__ Gv, const unsigned short* __restrict__ Pv,
             const unsigned short* __restrict__ Ga, const unsigned short* __restrict__ Pa,
             const unsigned short* __restrict__ Sa, const unsigned short* __restrict__ Cv,
             const unsigned short* __restrict__ Sv, const unsigned short* __restrict__ Ca,
             float* __restrict__ out)
{
    __shared__ __align__(16) unsigned short As[2 * 128 * 64];
    __shared__ __align__(16) unsigned short Bs[2 * 128 * 64];
    const unsigned short *A1, *B1, *A2, *B2; int D1, D2;
    if (blockIdx.z == 0) { A1 = Gv; B1 = Pv; D1 = CDV; A2 = Sa; B2 = Cv; D2 = CDA; }
    else                 { A1 = Ga; B1 = Pa; D1 = CDA; A2 = Sv; B2 = Ca; D2 = CDV; }

    f4v acc1[4][4] = {};
    f4v acc2[4][4] = {};
    int tid = threadIdx.x;
    int bm = blockIdx.x * 128, bn = blockIdx.y * 128;

    gemm_phase(A1, B1, D1, bm, bn, tid, As, Bs, acc1);   // intra
    gemm_phase(A2, B2, D2, bm, bn, tid, As, Bs, acc2);   // cross

    float local = 0.f;
#pragma unroll
    for (int i = 0; i < 4; ++i)
#pragma unroll
        for (int j = 0; j < 4; ++j)
#pragma unroll
            for (int e = 0; e < 4; ++e) {
                float iv = acc1[i][j][e];
                float cv = acc2[i][j][e];
                float sal = 0.3f * cv * cv + 0.7f * iv * iv;
                float t   = sal * iv;
                local += fmaxf(t, 0.f) + __logf(1.f + __expf(-fabsf(t)));
            }
#pragma unroll
    for (int o = 32; o > 0; o >>= 1) local += __shfl_down(local, o);
    __shared__ float wred[4];
    int lane = tid & 63, w = tid >> 6;
    if (lane == 0) wred[w] = local;
    __syncthreads();
    if (tid == 0) atomicAdd(out, -(wred[0] + wred[1] + wred[2] + wred[3]));
}

// ---------- launch ----------
extern "C" void kernel_launch(void* const* d_in, const int* in_sizes, int n_in,
                              void* d_out, int out_size, void* d_ws, size_t ws_size,
                              hipStream_t stream)
{
    const float* fv = (const float*)d_in[0];   // (8,2048,768)
    const float* fa = (const float*)d_in[1];   // (8,2048,512)
    const float* pv = (const float*)d_in[2];   // (512,768)
    const float* pa = (const float*)d_in[3];   // (512,512)
    const float* wv = (const float*)d_in[4];   // (768,512) proj_audio_to_vision
    const float* wa = (const float*)d_in[5];   // (512,768) proj_vision_to_audio
    float* out = (float*)d_out;

    size_t off = 0;
    auto carve = [&](size_t elems) {
        unsigned short* p = (unsigned short*)((char*)d_ws + off);
        off += ((elems * 2 + 255) & ~(size_t)255);
        return p;
    };
    unsigned short* Gv  = carve((size_t)CM * CDV);
    unsigned short* Sv  = carve((size_t)CM * CDV);
    unsigned short* Ga  = carve((size_t)CM * CDA);
    unsigned short* Sa  = carve((size_t)CM * CDA);
    unsigned short* Pv  = carve((size_t)CK * CDV);
    unsigned short* Pa  = carve((size_t)CK * CDA);
    unsigned short* WvT = carve((size_t)CDA * CDV);
    unsigned short* WaT = carve((size_t)CDV * CDA);
    unsigned short* Cv  = carve((size_t)CK * CDA);
    unsigned short* Ca  = carve((size_t)CK * CDV);

    hipMemsetAsync(d_out, 0, sizeof(float), stream);

    constexpr int NS = CM * (CDV / 4) + CM * (CDA / 4);
    prep_smooth_all<<<(NS + 255) / 256, 256, 0, stream>>>(fv, fa, Gv, Sv, Ga, Sa);

    constexpr int NP = CK * CDV / 4 + CK * CDA / 4 + 2 * CDV * CDA;
    prep_small<<<(NP + 255) / 256, 256, 0, stream>>>(pv, pa, wv, wa, Pv, Pa, WvT, WaT);

    gemm_combine2<<<16 + 24, 256, 0, stream>>>(Pv, WvT, Cv, Pa, WaT, Ca);

    fused_energy<<<dim3(CM / 128, CK / 128, 2), 256, 0, stream>>>(
        Gv, Pv, Ga, Pa, Sa, Cv, Sv, Ca, out);
}

// Round 5
// 181.791 us; speedup vs baseline: 1.2864x; 1.2864x over previous
//
#include <hip/hip_runtime.h>
#include <hip/hip_bf16.h>
#include <cmath>

// ---------- problem constants ----------
constexpr int CB = 8, CS = 2048, CDV = 768, CDA = 512, CK = 512;
constexpr int CM = CB * CS;             // 16384 rows (b,s)

// ---------- types ----------
typedef __attribute__((ext_vector_type(4))) float f4v;   // MFMA acc / fp32 loads
typedef __attribute__((ext_vector_type(4))) int   i4v;   // 16B LDS read
typedef __attribute__((ext_vector_type(8))) int   v8i;   // fp8 MFMA A/B frag (32 bytes)

template<bool HI>
__device__ __forceinline__ unsigned int pk2(float a, float b, unsigned int old) {
    return (unsigned int)__builtin_amdgcn_cvt_pk_fp8_f32(a, b, (int)old, HI);
}
__device__ __forceinline__ unsigned char f2f8(float x) {
    return (unsigned char)(__builtin_amdgcn_cvt_pk_fp8_f32(x, 0.f, 0, false) & 0xFF);
}

// ---------- prep: fp8 convert + window-3 temporal smooth (both modalities) ----------
template<int D>
__device__ __forceinline__ void smooth8(const float* __restrict__ f,
                                        unsigned char* __restrict__ g,
                                        unsigned char* __restrict__ sm,
                                        int idx)
{
    int dch = idx % (D / 8);
    int bs  = idx / (D / 8);
    int t   = bs % CS;
    const f4v* fp = (const f4v*)f;
    int b4 = bs * (D / 4) + dch * 2;
    f4v c0 = fp[b4], c1 = fp[b4 + 1];
    f4v a0 = c0, a1 = c1;
    float cnt = 1.f;
    if (t > 0)      { a0 += fp[b4 - D / 4]; a1 += fp[b4 - D / 4 + 1]; cnt += 1.f; }
    if (t < CS - 1) { a0 += fp[b4 + D / 4]; a1 += fp[b4 + D / 4 + 1]; cnt += 1.f; }
    float inv = 1.f / cnt;

    unsigned int glo = pk2<false>(c0[0], c0[1], 0u); glo = pk2<true>(c0[2], c0[3], glo);
    unsigned int ghi = pk2<false>(c1[0], c1[1], 0u); ghi = pk2<true>(c1[2], c1[3], ghi);
    unsigned int slo = pk2<false>(a0[0] * inv, a0[1] * inv, 0u); slo = pk2<true>(a0[2] * inv, a0[3] * inv, slo);
    unsigned int shi = pk2<false>(a1[0] * inv, a1[1] * inv, 0u); shi = pk2<true>(a1[2] * inv, a1[3] * inv, shi);
    ((uint2*)g)[idx]  = make_uint2(glo, ghi);
    ((uint2*)sm)[idx] = make_uint2(slo, shi);
}

__global__ void prep_smooth_all(const float* __restrict__ fv, const float* __restrict__ fa,
                                unsigned char* __restrict__ Gv, unsigned char* __restrict__ Sv,
                                unsigned char* __restrict__ Ga, unsigned char* __restrict__ Sa)
{
    int idx = blockIdx.x * 256 + threadIdx.x;
    constexpr int NV = CM * (CDV / 8);
    constexpr int NA = CM * (CDA / 8);
    if (idx < NV)            smooth8<CDV>(fv, Gv, Sv, idx);
    else if (idx < NV + NA)  smooth8<CDA>(fa, Ga, Sa, idx - NV);
}

// ---------- small prep: proto fp8 convert + proj transpose->fp8 (one launch) ----------
__device__ __forceinline__ void conv8(const float* __restrict__ in,
                                      unsigned char* __restrict__ out, int i)
{
    const f4v* fp = (const f4v*)in;
    f4v c0 = fp[2 * i], c1 = fp[2 * i + 1];
    unsigned int lo = pk2<false>(c0[0], c0[1], 0u); lo = pk2<true>(c0[2], c0[3], lo);
    unsigned int hi = pk2<false>(c1[0], c1[1], 0u); hi = pk2<true>(c1[2], c1[3], hi);
    ((uint2*)out)[i] = make_uint2(lo, hi);
}

__global__ void prep_small(const float* __restrict__ pv, const float* __restrict__ pa,
                           const float* __restrict__ wv, const float* __restrict__ wa,
                           unsigned char* __restrict__ Pv, unsigned char* __restrict__ Pa,
                           unsigned char* __restrict__ WvT, unsigned char* __restrict__ WaT)
{
    int idx = blockIdx.x * 256 + threadIdx.x;
    constexpr int N1 = CK * CDV / 8;
    constexpr int N2 = CK * CDA / 8;
    constexpr int N3 = CDV * CDA;
    if (idx < N1) { conv8(pv, Pv, idx); return; }
    idx -= N1;
    if (idx < N2) { conv8(pa, Pa, idx); return; }
    idx -= N2;
    if (idx < N3) {   // wv (768x512) -> WvT (512x768)
        int r = idx % CDV, c = idx / CDV;
        WvT[(size_t)c * CDV + r] = f2f8(wv[(size_t)r * CDA + c]);
        return;
    }
    idx -= N3;
    if (idx < N3) {   // wa (512x768) -> WaT (768x512)
        int r = idx % CDA, c = idx / CDA;
        WaT[(size_t)c * CDA + r] = f2f8(wa[(size_t)r * CDV + c]);
    }
}

// ---------- fp8 MX GEMM tile engine: acc += A(M,D) @ BT(N,D)^T on 128x128 tile ----------
// 256 threads = 4 waves; wave owns 64x64 = 4x4 frags of mfma_scale 16x16x128 fp8 (unit scales).
// K-step = 128 bytes/row; LDS [128 rows][128 B] per matrix per buffer (16 KB).
// Both-sides chunk swizzle: LDS slot (row, c) holds global chunk c^(row&7);
// reads fetch c_lds = cg ^ (row&7)  -> conflict-free b128 pattern.
// 2-phase double-buffer: STAGE(next) issued before ds_read+MFMA of current.
__device__ __forceinline__ v8i ld_frag(const unsigned char* base, int row, int hi)
{
    int c0 = (2 * hi) ^ (row & 7);          // global chunk 2*hi   -> k bytes [32hi,32hi+16)
    int c1 = c0 ^ 1;                        // global chunk 2*hi+1 -> k bytes [32hi+16,32hi+32)
    i4v lo = *(const i4v*)(base + row * 128 + c0 * 16);
    i4v h  = *(const i4v*)(base + row * 128 + c1 * 16);
    v8i r;
    r[0] = lo[0]; r[1] = lo[1]; r[2] = lo[2]; r[3] = lo[3];
    r[4] = h[0];  r[5] = h[1];  r[6] = h[2];  r[7] = h[3];
    return r;
}

__device__ __forceinline__ void gemm_phase_fp8(
    const unsigned char* __restrict__ A,
    const unsigned char* __restrict__ BT,
    int D, int bm, int bn, int tid,
    unsigned char* As, unsigned char* Bs,   // each 2 * 16384 bytes
    f4v (&acc)[4][4])
{
    const int lane = tid & 63;
    const int w    = tid >> 6;
    const int wr   = (w >> 1) * 64;
    const int wc   = (w & 1) * 64;
    const int lr   = lane & 15;
    const int hi   = lane >> 4;

    // hoisted per-thread staging bases
    const unsigned char* gA[4];
    const unsigned char* gB[4];
    int wb[4];
#pragma unroll
    for (int it = 0; it < 4; ++it) {
        int idx = it * 256 + tid;
        int row = idx >> 3;
        int sch = (idx & 7) ^ (row & 7);            // pre-swizzled source chunk
        wb[it]  = (idx & ~63) * 16;                 // wave-uniform LDS byte base
        gA[it]  = A  + (size_t)(bm + row) * D + sch * 16;
        gB[it]  = BT + (size_t)(bn + row) * D + sch * 16;
    }

    auto stage = [&](int buf, int d0) {
#pragma unroll
        for (int it = 0; it < 4; ++it) {
            __builtin_amdgcn_global_load_lds(
                (const __attribute__((address_space(1))) unsigned int*)(gA[it] + d0),
                (__attribute__((address_space(3))) unsigned int*)(As + buf * 16384 + wb[it]),
                16, 0, 0);
            __builtin_amdgcn_global_load_lds(
                (const __attribute__((address_space(1))) unsigned int*)(gB[it] + d0),
                (__attribute__((address_space(3))) unsigned int*)(Bs + buf * 16384 + wb[it]),
                16, 0, 0);
        }
    };

    __syncthreads();                   // all waves done with LDS from previous phase
    stage(0, 0);
    asm volatile("s_waitcnt vmcnt(0)" ::: "memory");
    __syncthreads();

    const int nt = D >> 7;
    int cur = 0;
    for (int t = 0; t < nt; ++t) {
        if (t + 1 < nt) stage(cur ^ 1, (t + 1) << 7);   // prefetch overlaps compute
        const unsigned char* Ab = As + cur * 16384;
        const unsigned char* Bb = Bs + cur * 16384;
        v8i af[4], bfr[4];
#pragma unroll
        for (int f = 0; f < 4; ++f) {
            af[f]  = ld_frag(Ab, wr + f * 16 + lr, hi);
            bfr[f] = ld_frag(Bb, wc + f * 16 + lr, hi);
        }
#pragma unroll
        for (int i = 0; i < 4; ++i)
#pragma unroll
            for (int j = 0; j < 4; ++j)
                acc[i][j] = __builtin_amdgcn_mfma_scale_f32_16x16x128_f8f6f4(
                    af[i], bfr[j], acc[i][j],
                    0, 0,                    // cbsz = FP8(e4m3), blgp = FP8(e4m3)
                    0, 0x7F7F7F7F,           // scale A: E8M0 127 = 1.0
                    0, 0x7F7F7F7F);          // scale B: E8M0 127 = 1.0
        if (t + 1 < nt) {
            asm volatile("s_waitcnt vmcnt(0)" ::: "memory");
            __syncthreads();
            cur ^= 1;
        }
    }
}

// ---------- combine GEMMs (both modalities, one launch), fp8 out ----------
__global__ void __launch_bounds__(256)
gemm_combine2(const unsigned char* __restrict__ Pv, const unsigned char* __restrict__ WvT,
              unsigned char* __restrict__ Cv,
              const unsigned char* __restrict__ Pa, const unsigned char* __restrict__ WaT,
              unsigned char* __restrict__ Ca)
{
    __shared__ __align__(16) unsigned char As[2 * 16384];
    __shared__ __align__(16) unsigned char Bs[2 * 16384];
    int id = blockIdx.x;
    const unsigned char *A, *BT; unsigned char* C; int D, N, bm, bn;
    if (id < 16) { A = Pv; BT = WvT; C = Cv; D = CDV; N = CDA; bm = (id & 3) * 128; bn = (id >> 2) * 128; }
    else { id -= 16; A = Pa; BT = WaT; C = Ca; D = CDA; N = CDV; bm = (id & 3) * 128; bn = (id >> 2) * 128; }

    f4v acc[4][4] = {};
    int tid = threadIdx.x;
    gemm_phase_fp8(A, BT, D, bm, bn, tid, As, Bs, acc);

    const int lane = tid & 63;
    const int w    = tid >> 6;
    const int wr   = (w >> 1) * 64, wc = (w & 1) * 64;
    const int row0 = (lane >> 4) * 4, col = lane & 15;   // C/D map: col=lane&15, row=(lane>>4)*4+e
#pragma unroll
    for (int i = 0; i < 4; ++i)
#pragma unroll
        for (int j = 0; j < 4; ++j)
#pragma unroll
            for (int e = 0; e < 4; ++e) {
                int m = bm + wr + i * 16 + row0 + e;
                int n = bn + wc + j * 16 + col;
                C[(size_t)m * N + n] = f2f8(acc[i][j][e]);
            }
}

// ---------- fused dual-GEMM + softplus-energy reduce (both modalities via z) ----------
__global__ void __launch_bounds__(256)
fused_energy(const unsigned char* __restrict__ Gv, const unsigned char* __restrict__ Pv,
             const unsigned char* __restrict__ Ga, const unsigned char* __restrict__ Pa,
             const unsigned char* __restrict__ Sa, const unsigned char* __restrict__ Cv,
             const unsigned char* __restrict__ Sv, const unsigned char* __restrict__ Ca,
             float* __restrict__ out)
{
    __shared__ __align__(16) unsigned char As[2 * 16384];
    __shared__ __align__(16) unsigned char Bs[2 * 16384];
    const unsigned char *A1, *B1, *A2, *B2; int D1, D2;
    if (blockIdx.z == 0) { A1 = Gv; B1 = Pv; D1 = CDV; A2 = Sa; B2 = Cv; D2 = CDA; }
    else                 { A1 = Ga; B1 = Pa; D1 = CDA; A2 = Sv; B2 = Ca; D2 = CDV; }

    f4v acc1[4][4] = {};
    f4v acc2[4][4] = {};
    int tid = threadIdx.x;
    int bm = blockIdx.x * 128, bn = blockIdx.y * 128;

    gemm_phase_fp8(A1, B1, D1, bm, bn, tid, As, Bs, acc1);   // intra
    gemm_phase_fp8(A2, B2, D2, bm, bn, tid, As, Bs, acc2);   // cross

    float local = 0.f;
#pragma unroll
    for (int i = 0; i < 4; ++i)
#pragma unroll
        for (int j = 0; j < 4; ++j)
#pragma unroll
            for (int e = 0; e < 4; ++e) {
                float iv = acc1[i][j][e];
                float cv = acc2[i][j][e];
                float sal = 0.3f * cv * cv + 0.7f * iv * iv;
                float t   = sal * iv;
                local += fmaxf(t, 0.f) + __logf(1.f + __expf(-fabsf(t)));
            }
#pragma unroll
    for (int o = 32; o > 0; o >>= 1) local += __shfl_down(local, o);
    __shared__ float wred[4];
    int lane = tid & 63, w = tid >> 6;
    if (lane == 0) wred[w] = local;
    __syncthreads();
    if (tid == 0) atomicAdd(out, -(wred[0] + wred[1] + wred[2] + wred[3]));
}

// ---------- launch ----------
extern "C" void kernel_launch(void* const* d_in, const int* in_sizes, int n_in,
                              void* d_out, int out_size, void* d_ws, size_t ws_size,
                              hipStream_t stream)
{
    const float* fv = (const float*)d_in[0];   // (8,2048,768)
    const float* fa = (const float*)d_in[1];   // (8,2048,512)
    const float* pv = (const float*)d_in[2];   // (512,768)
    const float* pa = (const float*)d_in[3];   // (512,512)
    const float* wv = (const float*)d_in[4];   // (768,512) proj_audio_to_vision
    const float* wa = (const float*)d_in[5];   // (512,768) proj_vision_to_audio
    float* out = (float*)d_out;

    size_t off = 0;
    auto carve = [&](size_t bytes) {
        unsigned char* p = (unsigned char*)d_ws + off;
        off += ((bytes + 255) & ~(size_t)255);
        return p;
    };
    unsigned char* Gv  = carve((size_t)CM * CDV);
    unsigned char* Sv  = carve((size_t)CM * CDV);
    unsigned char* Ga  = carve((size_t)CM * CDA);
    unsigned char* Sa  = carve((size_t)CM * CDA);
    unsigned char* Pv  = carve((size_t)CK * CDV);
    unsigned char* Pa  = carve((size_t)CK * CDA);
    unsigned char* WvT = carve((size_t)CDA * CDV);
    unsigned char* WaT = carve((size_t)CDV * CDA);
    unsigned char* Cv  = carve((size_t)CK * CDA);
    unsigned char* Ca  = carve((size_t)CK * CDV);

    (void)hipMemsetAsync(d_out, 0, sizeof(float), stream);

    constexpr int NS = CM * (CDV / 8) + CM * (CDA / 8);
    prep_smooth_all<<<(NS + 255) / 256, 256, 0, stream>>>(fv, fa, Gv, Sv, Ga, Sa);

    constexpr int NP = CK * CDV / 8 + CK * CDA / 8 + 2 * CDV * CDA;
    prep_small<<<(NP + 255) / 256, 256, 0, stream>>>(pv, pa, wv, wa, Pv, Pa, WvT, WaT);

    gemm_combine2<<<16 + 24, 256, 0, stream>>>(Pv, WvT, Cv, Pa, WaT, Ca);

    fused_energy<<<dim3(CM / 128, CK / 128, 2), 256, 0, stream>>>(
        Gv, Pv, Ga, Pa, Sa, Cv, Sv, Ca, out);
}